// Round 9
// baseline (287.623 us; speedup 1.0000x reference)
//
#include <hip/hip_runtime.h>

#define NN 400
#define HID 96
#define EDGES 79800
#define BATCH 16
#define ROWS (BATCH*EDGES)
#define NT 13            // node tiles of 32 (tile 12 half-padded)
#define NPAIRS 91        // NT*(NT+1)/2

typedef _Float16 f16;
typedef f16 f16x2 __attribute__((ext_vector_type(2)));
typedef f16 f16x8 __attribute__((ext_vector_type(8)));
typedef __fp16 fp16x2 __attribute__((ext_vector_type(2)));
typedef float f32x16 __attribute__((ext_vector_type(16)));
typedef unsigned int u32;
typedef unsigned long long u64;

union H8 { f16x8 h; u32 u[4]; f16x2 p[4]; fp16x2 q[4]; u64 d[2]; };
union C2 { f16x2 h; fp16x2 q; u32 u; };

__device__ inline f16x2 pkrtz(float a, float b) {
  C2 c; c.q = __builtin_amdgcn_cvt_pkrtz(a, b); return c.h;
}
__device__ inline u32 pkrtz_u(float a, float b) {
  C2 c; c.q = __builtin_amdgcn_cvt_pkrtz(a, b); return c.u;
}
__device__ inline float fdot2a(f16x2 a, f16x2 b, float c) {
#if __has_builtin(__builtin_amdgcn_fdot2)
  C2 ca, cb; ca.h = a; cb.h = b;
  return __builtin_amdgcn_fdot2(ca.q, cb.q, c, false);
#else
  return c + (float)a.x*(float)b.x + (float)a.y*(float)b.y;
#endif
}

__device__ inline f16x8 habs8(f16x8 x) {
  H8 t; t.h = x;
  t.u[0] &= 0x7fff7fffu; t.u[1] &= 0x7fff7fffu;
  t.u[2] &= 0x7fff7fffu; t.u[3] &= 0x7fff7fffu;
  return t.h;
}

__device__ inline f16x8 pack8(float a0,float a1,float a2,float a3,
                              float a4,float a5,float a6,float a7){
  H8 u;
  u.p[0] = pkrtz(a0,a1);
  u.p[1] = pkrtz(a2,a3);
  u.p[2] = pkrtz(a4,a5);
  u.p[3] = pkrtz(a6,a7);
  return u.h;
}

// ---------------- fused prep (blocks 0..139) + per-batch partial mean (blocks 140..395) --------
// wq regions (dwords): Wd1 [0,9216)  Wd2-permK [9216,11264)  We1 [11264,31232)  We2 [31232,35840)
__global__ void prep_mean_kernel(const float* __restrict__ We1, const float* __restrict__ We2,
                                 const float* __restrict__ W1, const float* __restrict__ W2,
                                 const float* __restrict__ sc,
                                 u32* __restrict__ wq, float* __restrict__ mpart) {
  if (blockIdx.x >= 140) {
    int p = blockIdx.x - 140;           // 0..255
    int b = p >> 4, part = p & 15;
    const float4* src = (const float4*)(sc + (size_t)b*160000) + part*2500;
    float s = 0.f;
    for (int i = threadIdx.x; i < 2500; i += 256) {
      float4 v = src[i];
      s += (v.x + v.y) + (v.z + v.w);
    }
    __shared__ float red[256];
    red[threadIdx.x] = s; __syncthreads();
    for (int off = 128; off > 0; off >>= 1) {
      if (threadIdx.x < off) red[threadIdx.x] += red[threadIdx.x + off];
      __syncthreads();
    }
    if (threadIdx.x == 0) mpart[p] = red[0];
    return;
  }
  int D = blockIdx.x*256 + threadIdx.x;     // 0..35839
  float v0, v1;
  if (D < 9216) {               // W_d1 B-frags (288 x 64), d = 32q+c
    int frag = D >> 8;  int t = frag >> 1, q = frag & 1;
    int rem = D & 255;  int lane = rem >> 2, dj = rem & 3;
    int c = lane & 31, h2 = lane >> 5;
    int k = 16*t + 8*h2 + 2*dj;
    int d = 32*q + c;
    v0 = W1[k*64 + d]; v1 = W1[(k+1)*64 + d];
  } else if (D < 11264) {       // W_d2 B-frags, K permuted: pair sources (p, p+32)
    int Dl = D - 9216;
    int frag = Dl >> 8; int t2 = frag >> 1, q = frag & 1;
    int rem = Dl & 255; int lane = rem >> 2, dj = rem & 3;
    int c = lane & 31, h2 = lane >> 5;
    int p = 8*t2 + 4*h2 + dj;
    int d = 32*q + c;
    v0 = W2[p*64 + d]; v1 = W2[(p+32)*64 + d];
  } else if (D < 31232) {       // W_e1 frags (416 x 96), sc features first, static at 400
    int Dl = D - 11264;
    int frag = Dl >> 8; int t = frag/3, ct = frag - 3*t;
    int rem = Dl & 255; int lane = rem >> 2, dj = rem & 3;
    int c = lane & 31, h2 = lane >> 5;
    int k0 = 16*t + 8*h2 + 2*dj, k1 = k0 + 1;
    int d = 32*ct + c;
    v0 = (k0 < 400) ? We1[(8+k0)*96 + d] : (k0 < 408 ? We1[(k0-400)*96 + d] : 0.f);
    v1 = (k1 < 400) ? We1[(8+k1)*96 + d] : (k1 < 408 ? We1[(k1-400)*96 + d] : 0.f);
  } else {                      // W_e2 frags (96 x 96), plain K order
    int Dl = D - 31232;
    int frag = Dl >> 8; int t = frag/3, ct = frag - 3*t;
    int rem = Dl & 255; int lane = rem >> 2, dj = rem & 3;
    int c = lane & 31, h2 = lane >> 5;
    int k = 16*t + 8*h2 + 2*dj;
    int d = 32*ct + c;
    v0 = We2[k*96 + d]; v1 = We2[(k+1)*96 + d];
  }
  wq[D] = pkrtz_u(v0, v1);
}

// ---------------- fused encoder, K-split across 4 waves (unchanged, measured OK) ---------------
__global__ __launch_bounds__(256) void enc_kernel(
    const float* __restrict__ sc, const float* __restrict__ nf,
    const float* __restrict__ smean, const float* __restrict__ sstd,
    const float* __restrict__ be1, const float* __restrict__ ae1,
    const float* __restrict__ be2, const float* __restrict__ ae2,
    const float* __restrict__ mpart, const u32* __restrict__ wq,
    f16* __restrict__ hout) {
  __shared__ u32 lds[12288 + 1664];
  const int tid = threadIdx.x;
  const int wid = tid >> 6, lane = tid & 63;
  const int c = lane & 31, h2 = lane >> 5;
  const int r0 = blockIdx.x * 32;
  {
    int row = tid >> 3, seg = tid & 7;
    int r = r0 + row;
    int b = r / 400;
    float ms = 0.f;
    const float4* mp4 = (const float4*)(mpart + 16*b);
#pragma unroll
    for (int k = 0; k < 4; ++k) { float4 v = mp4[k]; ms += (v.x+v.y)+(v.z+v.w); }
    float rm = 1.f / fmaxf(ms*(1.f/160000.f), 1e-8f);
    const float4* src = (const float4*)(sc + (size_t)r*400);
#pragma unroll
    for (int i = 0; i < 13; ++i) {
      int col4 = seg + 8*i;
      if (col4 < 100) {
        float4 v = src[col4];
        u32 lo = pkrtz_u(v.x*rm, v.y*rm);
        u32 hi = pkrtz_u(v.z*rm, v.w*rm);
        *(u64*)(lds + row*210 + col4*2) = (u64)lo | ((u64)hi << 32);
      }
    }
  }
  __syncthreads();
  int tb = (wid==0) ? 0 : (wid==1) ? 7 : (wid==2) ? 14 : 20;
  int te = (wid==0) ? 7 : (wid==1) ? 14 : (wid==2) ? 20 : 26;
  f32x16 acc[3] = {};
  const u32* wb1 = wq + 11264;
  for (int t = tb; t < te; ++t) {
    f16x8 af;
    if (t < 25) {
      H8 av;
      const u32* ap = lds + c*210 + 8*t + 4*h2;
      av.d[0] = *(const u64*)ap;
      av.d[1] = *(const u64*)(ap + 2);
      af = av.h;
    } else {
      af = (f16x8){};
      if (h2 == 0) {
        int r = r0 + c;
        float q0[8];
#pragma unroll
        for (int j = 0; j < 8; ++j)
          q0[j] = (nf[r*8 + j] - smean[j]) / (sstd[j] + 1e-8f);
        af = pack8(q0[0],q0[1],q0[2],q0[3],q0[4],q0[5],q0[6],q0[7]);
      }
    }
#pragma unroll
    for (int ct = 0; ct < 3; ++ct) {
      f16x8 bf = *(const f16x8*)(wb1 + ((t*3+ct)*64 + lane)*4);
      acc[ct] = __builtin_amdgcn_mfma_f32_32x32x16_f16(af, bf, acc[ct], 0,0,0);
    }
  }
  __syncthreads();
#pragma unroll
  for (int ct = 0; ct < 3; ++ct) {
    union { f32x16 v; float4 f[4]; } u; u.v = acc[ct];
#pragma unroll
    for (int i4 = 0; i4 < 4; ++i4)
      *(float4*)(lds + (((wid*3+ct)*4 + i4)*64 + lane)*4) = u.f[i4];
  }
  __syncthreads();
  f16* zb16 = (f16*)(lds + 12288);
  const float a1 = *ae1;
  if (wid < 3) {
    float bv = be1[32*wid + c];
    f32x16 s;
#pragma unroll
    for (int i = 0; i < 16; ++i) s[i] = bv;
#pragma unroll
    for (int w2 = 0; w2 < 4; ++w2) {
#pragma unroll
      for (int i4 = 0; i4 < 4; ++i4) {
        float4 f = *(const float4*)(lds + (((w2*3+wid)*4 + i4)*64 + lane)*4);
        s[4*i4+0] += f.x; s[4*i4+1] += f.y; s[4*i4+2] += f.z; s[4*i4+3] += f.w;
      }
    }
#pragma unroll
    for (int r = 0; r < 16; ++r) {
      float v = s[r]; v = fmaxf(v, a1*v);
      int row = (r & 3) + 8*(r >> 2) + 4*h2;
      zb16[row*104 + 32*wid + c] = (f16)v;
    }
  }
  __syncthreads();
  if (wid < 3) {
    const float a2 = *ae2;
    float bv = be2[32*wid + c];
    f32x16 acc2;
#pragma unroll
    for (int i = 0; i < 16; ++i) acc2[i] = bv;
    const u32* wb2 = wq + 31232;
#pragma unroll
    for (int t = 0; t < 6; ++t) {
      f16x8 af = *(const f16x8*)(zb16 + c*104 + 16*t + 8*h2);
      f16x8 bf = *(const f16x8*)(wb2 + ((t*3+wid)*64 + lane)*4);
      acc2 = __builtin_amdgcn_mfma_f32_32x32x16_f16(af, bf, acc2, 0,0,0);
    }
#pragma unroll
    for (int rr = 0; rr < 16; ++rr) {
      int row = (rr & 3) + 8*(rr >> 2) + 4*h2;
      float v = acc2[rr]; v = fmaxf(v, a2*v);
      hout[(r0 + row)*96 + 32*wid + c] = (f16)v;
    }
  }
}

// ---------------- decoder v3: tile-pair, conflict-free hJ frags, hI from global --------------
// LDS (dwords): hJ frag-major [0,1536)  Wd1 ksteps 0..13 [1536,8704)  zbuf [8704,13312)
//             = 53,248 B -> exactly 3 blocks/CU. Wd1 ksteps 14..17 + all Wd2 in registers.
// hJ frag-major: 16B chunk (q=2t+h2, c) at dword (q*32+c)*4 -> lane-contiguous b128 (0 conflicts).
// hI read from global: wave-broadcast address, tile-I is L1-resident (6 KB).
__global__ __launch_bounds__(256, 3) void decoder_kernel(
    const f16* __restrict__ hbuf, const u32* __restrict__ wq,
    const float* __restrict__ b1, const float* __restrict__ b2,
    const float* __restrict__ ad1, const float* __restrict__ ad2,
    const float* __restrict__ W3, const float* __restrict__ b3p,
    float* __restrict__ out) {
  __shared__ alignas(16) u32 smem[13312];
  const int tid = threadIdx.x;
  // task decode
  int p = blockIdx.x;
  int b = p / NPAIRS, pr = p - b*NPAIRS;
  int I = 0;
  while (pr >= NT - I) { pr -= NT - I; ++I; }
  const int J = I + pr;
  // stage hJ tile into frag-major layout: chunk q (=2t+h2) of row rr -> dword (q*32+rr)*4
  {
    int rr = tid >> 3, q0 = tid & 7;
    int nb = J*32 + rr;
    nb = nb < NN ? nb : NN-1;
    const f16* srow = hbuf + (size_t)(b*NN + nb)*HID;
#pragma unroll
    for (int i = 0; i < 2; ++i) {
      int q = q0 + 8*i;
      if (q < 12)
        *(float4*)(smem + (q*32 + rr)*4) = *(const float4*)(srow + q*8);
    }
  }
  // stage Wd1 ksteps 0..13 (1792 float4)
  {
    float4* dst = (float4*)(smem + 1536);
    const float4* srcw = (const float4*)wq;
#pragma unroll
    for (int k = 0; k < 7; ++k) dst[tid + 256*k] = srcw[tid + 256*k];
  }
  __syncthreads();

  const int lane = tid & 63;
  const int wid  = tid >> 6;
  const int c = lane & 31, h2 = lane >> 5;
  const f16* hJf = (const f16*)smem;
  const f16* wfr = (const f16*)(smem + 1536);
  u32* zb = smem + 8704 + wid*1152;
  // register frags: Wd1 ksteps 14..17 (prod t=2..5) + all Wd2
  f16x8 bpr[4][2];
#pragma unroll
  for (int s = 0; s < 4; ++s) {
    bpr[s][0] = *(const f16x8*)(wq + (((14+s)*2+0)*64 + lane)*4);
    bpr[s][1] = *(const f16x8*)(wq + (((14+s)*2+1)*64 + lane)*4);
  }
  f16x8 w2f[4][2];
#pragma unroll
  for (int t2 = 0; t2 < 4; ++t2) {
    w2f[t2][0] = *(const f16x8*)(wq + 9216 + ((t2*2+0)*64 + lane)*4);
    w2f[t2][1] = *(const f16x8*)(wq + 9216 + ((t2*2+1)*64 + lane)*4);
  }
  const float b1x = b1[c], b1y = b1[c+32];
  const float b2x = b2[c], b2y = b2[c+32];
  const float a1 = *ad1, a2 = *ad2, b3 = *b3p;
  const f16x2 a1v = pkrtz(a1, a1);
  const f16x2 a2v = pkrtz(a2, a2);
  const f16x2 w3p = pkrtz(W3[c], W3[c+32]);
  const f16x2 ones2 = pkrtz(1.f, 1.f);
  const int gj = J*32 + c;
  const int bofs = b*EDGES;
  const f16* hIbase = hbuf + (size_t)(b*NN)*HID + 8*h2;

  for (int it = 0; it < 4; ++it) {
    const int i0 = it*8 + wid*2;                // i_loc for m=0 (m adds 1)
    int gi0 = I*32 + i0;
    const f16* hi0p = hIbase + (size_t)(gi0     < NN ? gi0   : NN-1)*HID;
    const f16* hi1p = hIbase + (size_t)(gi0 + 1 < NN ? gi0+1 : NN-1)*HID;
    f32x16 acc[2][2];
#pragma unroll
    for (int r = 0; r < 16; ++r) {
      acc[0][0][r] = b1x; acc[0][1][r] = b1y;
      acc[1][0][r] = b1x; acc[1][1][r] = b1y;
    }
    // layer 1: K=288 = 6 octet-steps x {sum, absdiff, prod}
#pragma unroll
    for (int t = 0; t < 6; ++t) {
      f16x8 bs0 = *(const f16x8*)(wfr + (((t   )*2+0)*64 + lane)*8);
      f16x8 bs1 = *(const f16x8*)(wfr + (((t   )*2+1)*64 + lane)*8);
      f16x8 bd0 = *(const f16x8*)(wfr + (((t+ 6)*2+0)*64 + lane)*8);
      f16x8 bd1 = *(const f16x8*)(wfr + (((t+ 6)*2+1)*64 + lane)*8);
      f16x8 bp0 = (t < 2) ? *(const f16x8*)(wfr + (((t+12)*2+0)*64 + lane)*8) : bpr[t-2][0];
      f16x8 bp1 = (t < 2) ? *(const f16x8*)(wfr + (((t+12)*2+1)*64 + lane)*8) : bpr[t-2][1];
      f16x8 hj = *(const f16x8*)(hJf + ((2*t + h2)*32 + c)*8);
#pragma unroll
      for (int m = 0; m < 2; ++m) {
        f16x8 hi = *(const f16x8*)((m ? hi1p : hi0p) + 16*t);
        f16x8 su = hi + hj;
        f16x8 di = habs8(hi - hj);
        f16x8 prd = hi * hj;
        acc[m][0] = __builtin_amdgcn_mfma_f32_32x32x16_f16(su, bs0, acc[m][0], 0,0,0);
        acc[m][1] = __builtin_amdgcn_mfma_f32_32x32x16_f16(su, bs1, acc[m][1], 0,0,0);
        acc[m][0] = __builtin_amdgcn_mfma_f32_32x32x16_f16(di, bd0, acc[m][0], 0,0,0);
        acc[m][1] = __builtin_amdgcn_mfma_f32_32x32x16_f16(di, bd1, acc[m][1], 0,0,0);
        acc[m][0] = __builtin_amdgcn_mfma_f32_32x32x16_f16(prd, bp0, acc[m][0], 0,0,0);
        acc[m][1] = __builtin_amdgcn_mfma_f32_32x32x16_f16(prd, bp1, acc[m][1], 0,0,0);
      }
    }
#pragma unroll
    for (int m = 0; m < 2; ++m) {
      // prelu(z1) packed-f16 -> LDS pairs (d, d+32) at dword [row][c], stride 36
#pragma unroll
      for (int r = 0; r < 16; ++r) {
        f16x2 pz = pkrtz(acc[m][0][r], acc[m][1][r]);
        pz = __builtin_elementwise_max(pz, pz * a1v);
        C2 cv; cv.h = pz;
        int row = (r & 3) + 8*(r >> 2) + 4*h2;
        zb[row*36 + c] = cv.u;
      }
      // read back as layer-2 A-frags (edge = c): permuted-K contiguous, aligned b128
      f16x8 za[4];
#pragma unroll
      for (int t2 = 0; t2 < 4; ++t2)
        za[t2] = *(const f16x8*)((const f16*)zb + (c*36 + 8*t2 + 4*h2)*2);
      f32x16 zacc[2];
#pragma unroll
      for (int r = 0; r < 16; ++r) { zacc[0][r] = b2x; zacc[1][r] = b2y; }
#pragma unroll
      for (int t2 = 0; t2 < 4; ++t2) {
        zacc[0] = __builtin_amdgcn_mfma_f32_32x32x16_f16(za[t2], w2f[t2][0], zacc[0], 0,0,0);
        zacc[1] = __builtin_amdgcn_mfma_f32_32x32x16_f16(za[t2], w2f[t2][1], zacc[1], 0,0,0);
      }
      // prelu(z2)*W3 packed -> LDS -> per-edge dot2 sum
#pragma unroll
      for (int r = 0; r < 16; ++r) {
        f16x2 pz = pkrtz(zacc[0][r], zacc[1][r]);
        pz = __builtin_elementwise_max(pz, pz * a2v);
        pz = pz * w3p;
        C2 cv; cv.h = pz;
        int row = (r & 3) + 8*(r >> 2) + 4*h2;
        zb[row*36 + c] = cv.u;
      }
      float ssum = 0.f;
#pragma unroll
      for (int g = 0; g < 4; ++g) {
        H8 v; v.h = *(const f16x8*)((const f16*)zb + (c*36 + 16*h2 + 4*g)*2);
#pragma unroll
        for (int dw = 0; dw < 4; ++dw)
          ssum = fdot2a(v.p[dw], ones2, ssum);
      }
      ssum += __shfl_xor(ssum, 32);
      // lane c holds edge (gi, gj=J*32+c); analytic triu index, coalesced in c
      int gi = I*32 + i0 + m;
      bool valid = (gi < gj) && (gj < NN);
      if (h2 == 0 && valid) {
        int eo = bofs + gi*(799 - gi)/2 + (gj - gi - 1);
        out[eo] = ssum + b3;
      }
    }
  }
}

extern "C" void kernel_launch(void* const* d_in, const int* in_sizes, int n_in,
                              void* d_out, int out_size, void* d_ws, size_t ws_size,
                              hipStream_t stream) {
  const float* nf  = (const float*)d_in[1];
  const float* sc  = (const float*)d_in[2];
  const float* sm  = (const float*)d_in[3];
  const float* ss  = (const float*)d_in[4];
  const float* We1 = (const float*)d_in[5];
  const float* be1 = (const float*)d_in[6];
  const float* ae1 = (const float*)d_in[7];
  const float* We2 = (const float*)d_in[8];
  const float* be2 = (const float*)d_in[9];
  const float* ae2 = (const float*)d_in[10];
  const float* W1  = (const float*)d_in[11];
  const float* b1  = (const float*)d_in[12];
  const float* a1  = (const float*)d_in[13];
  const float* W2  = (const float*)d_in[14];
  const float* b2  = (const float*)d_in[15];
  const float* a2  = (const float*)d_in[16];
  const float* W3  = (const float*)d_in[17];
  const float* b3  = (const float*)d_in[18];
  float* out = (float*)d_out;

  char* ws = (char*)d_ws;
  float* mpart = (float*)ws;                             // 256 f32 = 1,024 B
  f16*   hbuf = (f16*)(ws + 1024);                       // 1,228,800 B
  u32*   wq   = (u32*)(ws + 1024 + 1228800);             // 143,360 B

  prep_mean_kernel<<<396, 256, 0, stream>>>(We1, We2, W1, W2, sc, wq, mpart);
  enc_kernel<<<200, 256, 0, stream>>>(sc, nf, sm, ss, be1, ae1, be2, ae2,
                                      mpart, wq, hbuf);
  decoder_kernel<<<BATCH*NPAIRS, 256, 0, stream>>>(hbuf, wq, b1, b2, a1, a2,
                                                   W3, b3, out);
}

// Round 10
// 186.183 us; speedup vs baseline: 1.5448x; 1.5448x over previous
//
#include <hip/hip_runtime.h>

#define NN 400
#define HID 96
#define EDGES 79800
#define BATCH 16
#define ROWS (BATCH*EDGES)
#define NT 13            // node tiles of 32 (tile 12 half-padded)
#define NPAIRS 91        // NT*(NT+1)/2

typedef _Float16 f16;
typedef f16 f16x2 __attribute__((ext_vector_type(2)));
typedef f16 f16x8 __attribute__((ext_vector_type(8)));
typedef __fp16 fp16x2 __attribute__((ext_vector_type(2)));
typedef float f32x16 __attribute__((ext_vector_type(16)));
typedef unsigned int u32;
typedef unsigned long long u64;

union H8 { f16x8 h; u32 u[4]; f16x2 p[4]; fp16x2 q[4]; u64 d[2]; };
union C2 { f16x2 h; fp16x2 q; u32 u; };

__device__ inline f16x2 pkrtz(float a, float b) {
  C2 c; c.q = __builtin_amdgcn_cvt_pkrtz(a, b); return c.h;
}
__device__ inline u32 pkrtz_u(float a, float b) {
  C2 c; c.q = __builtin_amdgcn_cvt_pkrtz(a, b); return c.u;
}
__device__ inline float fdot2a(f16x2 a, f16x2 b, float c) {
#if __has_builtin(__builtin_amdgcn_fdot2)
  C2 ca, cb; ca.h = a; cb.h = b;
  return __builtin_amdgcn_fdot2(ca.q, cb.q, c, false);
#else
  return c + (float)a.x*(float)b.x + (float)a.y*(float)b.y;
#endif
}

__device__ inline f16x8 habs8(f16x8 x) {
  H8 t; t.h = x;
  t.u[0] &= 0x7fff7fffu; t.u[1] &= 0x7fff7fffu;
  t.u[2] &= 0x7fff7fffu; t.u[3] &= 0x7fff7fffu;
  return t.h;
}

__device__ inline f16x8 pack8(float a0,float a1,float a2,float a3,
                              float a4,float a5,float a6,float a7){
  H8 u;
  u.p[0] = pkrtz(a0,a1);
  u.p[1] = pkrtz(a2,a3);
  u.p[2] = pkrtz(a4,a5);
  u.p[3] = pkrtz(a6,a7);
  return u.h;
}

// ---------------- fused prep (blocks 0..139) + per-batch partial mean (blocks 140..395) --------
// wq regions (dwords): Wd1 [0,9216)  Wd2-permK [9216,11264)  We1 [11264,31232)  We2 [31232,35840)
__global__ void prep_mean_kernel(const float* __restrict__ We1, const float* __restrict__ We2,
                                 const float* __restrict__ W1, const float* __restrict__ W2,
                                 const float* __restrict__ sc,
                                 u32* __restrict__ wq, float* __restrict__ mpart) {
  if (blockIdx.x >= 140) {
    int p = blockIdx.x - 140;           // 0..255
    int b = p >> 4, part = p & 15;
    const float4* src = (const float4*)(sc + (size_t)b*160000) + part*2500;
    float s = 0.f;
    for (int i = threadIdx.x; i < 2500; i += 256) {
      float4 v = src[i];
      s += (v.x + v.y) + (v.z + v.w);
    }
    __shared__ float red[256];
    red[threadIdx.x] = s; __syncthreads();
    for (int off = 128; off > 0; off >>= 1) {
      if (threadIdx.x < off) red[threadIdx.x] += red[threadIdx.x + off];
      __syncthreads();
    }
    if (threadIdx.x == 0) mpart[p] = red[0];
    return;
  }
  int D = blockIdx.x*256 + threadIdx.x;     // 0..35839
  float v0, v1;
  if (D < 9216) {               // W_d1 B-frags (288 x 64), d = 32q+c
    int frag = D >> 8;  int t = frag >> 1, q = frag & 1;
    int rem = D & 255;  int lane = rem >> 2, dj = rem & 3;
    int c = lane & 31, h2 = lane >> 5;
    int k = 16*t + 8*h2 + 2*dj;
    int d = 32*q + c;
    v0 = W1[k*64 + d]; v1 = W1[(k+1)*64 + d];
  } else if (D < 11264) {       // W_d2 B-frags, K permuted: pair sources (p, p+32)
    int Dl = D - 9216;
    int frag = Dl >> 8; int t2 = frag >> 1, q = frag & 1;
    int rem = Dl & 255; int lane = rem >> 2, dj = rem & 3;
    int c = lane & 31, h2 = lane >> 5;
    int p = 8*t2 + 4*h2 + dj;
    int d = 32*q + c;
    v0 = W2[p*64 + d]; v1 = W2[(p+32)*64 + d];
  } else if (D < 31232) {       // W_e1 frags (416 x 96), sc features first, static at 400
    int Dl = D - 11264;
    int frag = Dl >> 8; int t = frag/3, ct = frag - 3*t;
    int rem = Dl & 255; int lane = rem >> 2, dj = rem & 3;
    int c = lane & 31, h2 = lane >> 5;
    int k0 = 16*t + 8*h2 + 2*dj, k1 = k0 + 1;
    int d = 32*ct + c;
    v0 = (k0 < 400) ? We1[(8+k0)*96 + d] : (k0 < 408 ? We1[(k0-400)*96 + d] : 0.f);
    v1 = (k1 < 400) ? We1[(8+k1)*96 + d] : (k1 < 408 ? We1[(k1-400)*96 + d] : 0.f);
  } else {                      // W_e2 frags (96 x 96), plain K order
    int Dl = D - 31232;
    int frag = Dl >> 8; int t = frag/3, ct = frag - 3*t;
    int rem = Dl & 255; int lane = rem >> 2, dj = rem & 3;
    int c = lane & 31, h2 = lane >> 5;
    int k = 16*t + 8*h2 + 2*dj;
    int d = 32*ct + c;
    v0 = We2[k*96 + d]; v1 = We2[(k+1)*96 + d];
  }
  wq[D] = pkrtz_u(v0, v1);
}

// ---------------- fused encoder, K-split across 4 waves (unchanged, measured OK) ---------------
__global__ __launch_bounds__(256) void enc_kernel(
    const float* __restrict__ sc, const float* __restrict__ nf,
    const float* __restrict__ smean, const float* __restrict__ sstd,
    const float* __restrict__ be1, const float* __restrict__ ae1,
    const float* __restrict__ be2, const float* __restrict__ ae2,
    const float* __restrict__ mpart, const u32* __restrict__ wq,
    f16* __restrict__ hout) {
  __shared__ u32 lds[12288 + 1664];
  const int tid = threadIdx.x;
  const int wid = tid >> 6, lane = tid & 63;
  const int c = lane & 31, h2 = lane >> 5;
  const int r0 = blockIdx.x * 32;
  {
    int row = tid >> 3, seg = tid & 7;
    int r = r0 + row;
    int b = r / 400;
    float ms = 0.f;
    const float4* mp4 = (const float4*)(mpart + 16*b);
#pragma unroll
    for (int k = 0; k < 4; ++k) { float4 v = mp4[k]; ms += (v.x+v.y)+(v.z+v.w); }
    float rm = 1.f / fmaxf(ms*(1.f/160000.f), 1e-8f);
    const float4* src = (const float4*)(sc + (size_t)r*400);
#pragma unroll
    for (int i = 0; i < 13; ++i) {
      int col4 = seg + 8*i;
      if (col4 < 100) {
        float4 v = src[col4];
        u32 lo = pkrtz_u(v.x*rm, v.y*rm);
        u32 hi = pkrtz_u(v.z*rm, v.w*rm);
        *(u64*)(lds + row*210 + col4*2) = (u64)lo | ((u64)hi << 32);
      }
    }
  }
  __syncthreads();
  int tb = (wid==0) ? 0 : (wid==1) ? 7 : (wid==2) ? 14 : 20;
  int te = (wid==0) ? 7 : (wid==1) ? 14 : (wid==2) ? 20 : 26;
  f32x16 acc[3] = {};
  const u32* wb1 = wq + 11264;
  for (int t = tb; t < te; ++t) {
    f16x8 af;
    if (t < 25) {
      H8 av;
      const u32* ap = lds + c*210 + 8*t + 4*h2;
      av.d[0] = *(const u64*)ap;
      av.d[1] = *(const u64*)(ap + 2);
      af = av.h;
    } else {
      af = (f16x8){};
      if (h2 == 0) {
        int r = r0 + c;
        float q0[8];
#pragma unroll
        for (int j = 0; j < 8; ++j)
          q0[j] = (nf[r*8 + j] - smean[j]) / (sstd[j] + 1e-8f);
        af = pack8(q0[0],q0[1],q0[2],q0[3],q0[4],q0[5],q0[6],q0[7]);
      }
    }
#pragma unroll
    for (int ct = 0; ct < 3; ++ct) {
      f16x8 bf = *(const f16x8*)(wb1 + ((t*3+ct)*64 + lane)*4);
      acc[ct] = __builtin_amdgcn_mfma_f32_32x32x16_f16(af, bf, acc[ct], 0,0,0);
    }
  }
  __syncthreads();
#pragma unroll
  for (int ct = 0; ct < 3; ++ct) {
    union { f32x16 v; float4 f[4]; } u; u.v = acc[ct];
#pragma unroll
    for (int i4 = 0; i4 < 4; ++i4)
      *(float4*)(lds + (((wid*3+ct)*4 + i4)*64 + lane)*4) = u.f[i4];
  }
  __syncthreads();
  f16* zb16 = (f16*)(lds + 12288);
  const float a1 = *ae1;
  if (wid < 3) {
    float bv = be1[32*wid + c];
    f32x16 s;
#pragma unroll
    for (int i = 0; i < 16; ++i) s[i] = bv;
#pragma unroll
    for (int w2 = 0; w2 < 4; ++w2) {
#pragma unroll
      for (int i4 = 0; i4 < 4; ++i4) {
        float4 f = *(const float4*)(lds + (((w2*3+wid)*4 + i4)*64 + lane)*4);
        s[4*i4+0] += f.x; s[4*i4+1] += f.y; s[4*i4+2] += f.z; s[4*i4+3] += f.w;
      }
    }
#pragma unroll
    for (int r = 0; r < 16; ++r) {
      float v = s[r]; v = fmaxf(v, a1*v);
      int row = (r & 3) + 8*(r >> 2) + 4*h2;
      zb16[row*104 + 32*wid + c] = (f16)v;
    }
  }
  __syncthreads();
  if (wid < 3) {
    const float a2 = *ae2;
    float bv = be2[32*wid + c];
    f32x16 acc2;
#pragma unroll
    for (int i = 0; i < 16; ++i) acc2[i] = bv;
    const u32* wb2 = wq + 31232;
#pragma unroll
    for (int t = 0; t < 6; ++t) {
      f16x8 af = *(const f16x8*)(zb16 + c*104 + 16*t + 8*h2);
      f16x8 bf = *(const f16x8*)(wb2 + ((t*3+wid)*64 + lane)*4);
      acc2 = __builtin_amdgcn_mfma_f32_32x32x16_f16(af, bf, acc2, 0,0,0);
    }
#pragma unroll
    for (int rr = 0; rr < 16; ++rr) {
      int row = (rr & 3) + 8*(rr >> 2) + 4*h2;
      float v = acc2[rr]; v = fmaxf(v, a2*v);
      hout[(r0 + row)*96 + 32*wid + c] = (f16)v;
    }
  }
}

// ---------------- decoder v4: v3 structure, launch_bounds(256,2) — NEVER 3 (R3/R9 spills) ------
// LDS (dwords): hJ frag-major padded [0,1584)  Wd1 ksteps 0..13 [1584,8752)  zbuf [8752,13360)
//             = 53,440 B -> 3 blocks/CU (with VGPR ~130-150 -> 3 waves/SIMD naturally).
// hJ layout: 16B chunk (q=2t+h2, row rr) at dword q*132 + rr*4 (132: 16B-aligned, 2-way-max banks).
// hI from global (wave-broadcast, L1-resident). Wd1 ksteps 14..17 + all Wd2 in registers.
__global__ __launch_bounds__(256, 2) void decoder_kernel(
    const f16* __restrict__ hbuf, const u32* __restrict__ wq,
    const float* __restrict__ b1, const float* __restrict__ b2,
    const float* __restrict__ ad1, const float* __restrict__ ad2,
    const float* __restrict__ W3, const float* __restrict__ b3p,
    float* __restrict__ out) {
  __shared__ alignas(16) u32 smem[13360];
  const int tid = threadIdx.x;
  // task decode
  int p = blockIdx.x;
  int b = p / NPAIRS, pr = p - b*NPAIRS;
  int I = 0;
  while (pr >= NT - I) { pr -= NT - I; ++I; }
  const int J = I + pr;
  // stage hJ tile into padded frag-major layout
  {
    int rr = tid >> 3, q0 = tid & 7;
    int nb = J*32 + rr;
    nb = nb < NN ? nb : NN-1;
    const f16* srow = hbuf + (size_t)(b*NN + nb)*HID;
#pragma unroll
    for (int i = 0; i < 2; ++i) {
      int q = q0 + 8*i;
      if (q < 12)
        *(float4*)(smem + q*132 + rr*4) = *(const float4*)(srow + q*8);
    }
  }
  // stage Wd1 ksteps 0..13 (1792 float4)
  {
    float4* dst = (float4*)(smem + 1584);
    const float4* srcw = (const float4*)wq;
#pragma unroll
    for (int k = 0; k < 7; ++k) dst[tid + 256*k] = srcw[tid + 256*k];
  }
  __syncthreads();

  const int lane = tid & 63;
  const int wid  = tid >> 6;
  const int c = lane & 31, h2 = lane >> 5;
  const f16* hJf = (const f16*)smem;
  const f16* wfr = (const f16*)(smem + 1584);
  u32* zb = smem + 8752 + wid*1152;
  // register frags: Wd1 ksteps 14..17 (prod t=2..5) + all Wd2
  f16x8 bpr[4][2];
#pragma unroll
  for (int s = 0; s < 4; ++s) {
    bpr[s][0] = *(const f16x8*)(wq + (((14+s)*2+0)*64 + lane)*4);
    bpr[s][1] = *(const f16x8*)(wq + (((14+s)*2+1)*64 + lane)*4);
  }
  f16x8 w2f[4][2];
#pragma unroll
  for (int t2 = 0; t2 < 4; ++t2) {
    w2f[t2][0] = *(const f16x8*)(wq + 9216 + ((t2*2+0)*64 + lane)*4);
    w2f[t2][1] = *(const f16x8*)(wq + 9216 + ((t2*2+1)*64 + lane)*4);
  }
  const float b1x = b1[c], b1y = b1[c+32];
  const float b2x = b2[c], b2y = b2[c+32];
  const float a1 = *ad1, a2 = *ad2, b3 = *b3p;
  const f16x2 a1v = pkrtz(a1, a1);
  const f16x2 a2v = pkrtz(a2, a2);
  const f16x2 w3p = pkrtz(W3[c], W3[c+32]);
  const f16x2 ones2 = pkrtz(1.f, 1.f);
  const int gj = J*32 + c;
  const int bofs = b*EDGES;
  const f16* hIbase = hbuf + (size_t)(b*NN)*HID + 8*h2;

  for (int it = 0; it < 4; ++it) {
    const int i0 = it*8 + wid*2;                // i_loc for m=0 (m adds 1)
    int gi0 = I*32 + i0;
    const f16* hi0p = hIbase + (size_t)(gi0     < NN ? gi0   : NN-1)*HID;
    const f16* hi1p = hIbase + (size_t)(gi0 + 1 < NN ? gi0+1 : NN-1)*HID;
    f32x16 acc[2][2];
#pragma unroll
    for (int r = 0; r < 16; ++r) {
      acc[0][0][r] = b1x; acc[0][1][r] = b1y;
      acc[1][0][r] = b1x; acc[1][1][r] = b1y;
    }
    // layer 1: K=288 = 6 octet-steps x {sum, absdiff, prod}
#pragma unroll
    for (int t = 0; t < 6; ++t) {
      f16x8 bs0 = *(const f16x8*)(wfr + (((t   )*2+0)*64 + lane)*8);
      f16x8 bs1 = *(const f16x8*)(wfr + (((t   )*2+1)*64 + lane)*8);
      f16x8 bd0 = *(const f16x8*)(wfr + (((t+ 6)*2+0)*64 + lane)*8);
      f16x8 bd1 = *(const f16x8*)(wfr + (((t+ 6)*2+1)*64 + lane)*8);
      f16x8 bp0 = (t < 2) ? *(const f16x8*)(wfr + (((t+12)*2+0)*64 + lane)*8) : bpr[t-2][0];
      f16x8 bp1 = (t < 2) ? *(const f16x8*)(wfr + (((t+12)*2+1)*64 + lane)*8) : bpr[t-2][1];
      f16x8 hj = *(const f16x8*)(hJf + (2*t + h2)*264 + c*8);
#pragma unroll
      for (int m = 0; m < 2; ++m) {
        f16x8 hi = *(const f16x8*)((m ? hi1p : hi0p) + 16*t);
        f16x8 su = hi + hj;
        f16x8 di = habs8(hi - hj);
        f16x8 prd = hi * hj;
        acc[m][0] = __builtin_amdgcn_mfma_f32_32x32x16_f16(su, bs0, acc[m][0], 0,0,0);
        acc[m][1] = __builtin_amdgcn_mfma_f32_32x32x16_f16(su, bs1, acc[m][1], 0,0,0);
        acc[m][0] = __builtin_amdgcn_mfma_f32_32x32x16_f16(di, bd0, acc[m][0], 0,0,0);
        acc[m][1] = __builtin_amdgcn_mfma_f32_32x32x16_f16(di, bd1, acc[m][1], 0,0,0);
        acc[m][0] = __builtin_amdgcn_mfma_f32_32x32x16_f16(prd, bp0, acc[m][0], 0,0,0);
        acc[m][1] = __builtin_amdgcn_mfma_f32_32x32x16_f16(prd, bp1, acc[m][1], 0,0,0);
      }
    }
#pragma unroll
    for (int m = 0; m < 2; ++m) {
      // prelu(z1) packed-f16 -> LDS pairs (d, d+32) at dword [row][c], stride 36
#pragma unroll
      for (int r = 0; r < 16; ++r) {
        f16x2 pz = pkrtz(acc[m][0][r], acc[m][1][r]);
        pz = __builtin_elementwise_max(pz, pz * a1v);
        C2 cv; cv.h = pz;
        int row = (r & 3) + 8*(r >> 2) + 4*h2;
        zb[row*36 + c] = cv.u;
      }
      // read back as layer-2 A-frags (edge = c): permuted-K contiguous, aligned b128
      f16x8 za[4];
#pragma unroll
      for (int t2 = 0; t2 < 4; ++t2)
        za[t2] = *(const f16x8*)((const f16*)zb + (c*36 + 8*t2 + 4*h2)*2);
      f32x16 zacc[2];
#pragma unroll
      for (int r = 0; r < 16; ++r) { zacc[0][r] = b2x; zacc[1][r] = b2y; }
#pragma unroll
      for (int t2 = 0; t2 < 4; ++t2) {
        zacc[0] = __builtin_amdgcn_mfma_f32_32x32x16_f16(za[t2], w2f[t2][0], zacc[0], 0,0,0);
        zacc[1] = __builtin_amdgcn_mfma_f32_32x32x16_f16(za[t2], w2f[t2][1], zacc[1], 0,0,0);
      }
      // prelu(z2)*W3 packed -> LDS -> per-edge dot2 sum
#pragma unroll
      for (int r = 0; r < 16; ++r) {
        f16x2 pz = pkrtz(zacc[0][r], zacc[1][r]);
        pz = __builtin_elementwise_max(pz, pz * a2v);
        pz = pz * w3p;
        C2 cv; cv.h = pz;
        int row = (r & 3) + 8*(r >> 2) + 4*h2;
        zb[row*36 + c] = cv.u;
      }
      float ssum = 0.f;
#pragma unroll
      for (int g = 0; g < 4; ++g) {
        H8 v; v.h = *(const f16x8*)((const f16*)zb + (c*36 + 16*h2 + 4*g)*2);
#pragma unroll
        for (int dw = 0; dw < 4; ++dw)
          ssum = fdot2a(v.p[dw], ones2, ssum);
      }
      ssum += __shfl_xor(ssum, 32);
      // lane c holds edge (gi, gj=J*32+c); analytic triu index, coalesced in c
      int gi = I*32 + i0 + m;
      bool valid = (gi < gj) && (gj < NN);
      if (h2 == 0 && valid) {
        int eo = bofs + gi*(799 - gi)/2 + (gj - gi - 1);
        out[eo] = ssum + b3;
      }
    }
  }
}

extern "C" void kernel_launch(void* const* d_in, const int* in_sizes, int n_in,
                              void* d_out, int out_size, void* d_ws, size_t ws_size,
                              hipStream_t stream) {
  const float* nf  = (const float*)d_in[1];
  const float* sc  = (const float*)d_in[2];
  const float* sm  = (const float*)d_in[3];
  const float* ss  = (const float*)d_in[4];
  const float* We1 = (const float*)d_in[5];
  const float* be1 = (const float*)d_in[6];
  const float* ae1 = (const float*)d_in[7];
  const float* We2 = (const float*)d_in[8];
  const float* be2 = (const float*)d_in[9];
  const float* ae2 = (const float*)d_in[10];
  const float* W1  = (const float*)d_in[11];
  const float* b1  = (const float*)d_in[12];
  const float* a1  = (const float*)d_in[13];
  const float* W2  = (const float*)d_in[14];
  const float* b2  = (const float*)d_in[15];
  const float* a2  = (const float*)d_in[16];
  const float* W3  = (const float*)d_in[17];
  const float* b3  = (const float*)d_in[18];
  float* out = (float*)d_out;

  char* ws = (char*)d_ws;
  float* mpart = (float*)ws;                             // 256 f32 = 1,024 B
  f16*   hbuf = (f16*)(ws + 1024);                       // 1,228,800 B
  u32*   wq   = (u32*)(ws + 1024 + 1228800);             // 143,360 B

  prep_mean_kernel<<<396, 256, 0, stream>>>(We1, We2, W1, W2, sc, wq, mpart);
  enc_kernel<<<200, 256, 0, stream>>>(sc, nf, sm, ss, be1, ae1, be2, ae2,
                                      mpart, wq, hbuf);
  decoder_kernel<<<BATCH*NPAIRS, 256, 0, stream>>>(hbuf, wq, b1, b2, a1, a2,
                                                   W3, b3, out);
}

// Round 11
// 185.582 us; speedup vs baseline: 1.5498x; 1.0032x over previous
//
#include <hip/hip_runtime.h>

#define NN 400
#define HID 96
#define EDGES 79800
#define BATCH 16
#define ROWS (BATCH*EDGES)
#define NT 13            // node tiles of 32 (tile 12 half-padded)
#define NPAIRS 91        // NT*(NT+1)/2

typedef _Float16 f16;
typedef f16 f16x2 __attribute__((ext_vector_type(2)));
typedef f16 f16x8 __attribute__((ext_vector_type(8)));
typedef __fp16 fp16x2 __attribute__((ext_vector_type(2)));
typedef float f32x16 __attribute__((ext_vector_type(16)));
typedef unsigned int u32;
typedef unsigned long long u64;

union H8 { f16x8 h; u32 u[4]; f16x2 p[4]; fp16x2 q[4]; u64 d[2]; };
union C2 { f16x2 h; fp16x2 q; u32 u; };

__device__ inline f16x2 pkrtz(float a, float b) {
  C2 c; c.q = __builtin_amdgcn_cvt_pkrtz(a, b); return c.h;
}
__device__ inline u32 pkrtz_u(float a, float b) {
  C2 c; c.q = __builtin_amdgcn_cvt_pkrtz(a, b); return c.u;
}
__device__ inline float fdot2a(f16x2 a, f16x2 b, float c) {
#if __has_builtin(__builtin_amdgcn_fdot2)
  C2 ca, cb; ca.h = a; cb.h = b;
  return __builtin_amdgcn_fdot2(ca.q, cb.q, c, false);
#else
  return c + (float)a.x*(float)b.x + (float)a.y*(float)b.y;
#endif
}

__device__ inline f16x8 habs8(f16x8 x) {
  H8 t; t.h = x;
  t.u[0] &= 0x7fff7fffu; t.u[1] &= 0x7fff7fffu;
  t.u[2] &= 0x7fff7fffu; t.u[3] &= 0x7fff7fffu;
  return t.h;
}

__device__ inline f16x8 pack8(float a0,float a1,float a2,float a3,
                              float a4,float a5,float a6,float a7){
  H8 u;
  u.p[0] = pkrtz(a0,a1);
  u.p[1] = pkrtz(a2,a3);
  u.p[2] = pkrtz(a4,a5);
  u.p[3] = pkrtz(a6,a7);
  return u.h;
}

// ---------------- fused prep (blocks 0..139) + per-batch partial mean (blocks 140..395) --------
// wq regions (dwords): Wd1 [0,9216)  Wd2-permK [9216,11264)  We1 [11264,31232)  We2 [31232,35840)
__global__ void prep_mean_kernel(const float* __restrict__ We1, const float* __restrict__ We2,
                                 const float* __restrict__ W1, const float* __restrict__ W2,
                                 const float* __restrict__ sc,
                                 u32* __restrict__ wq, float* __restrict__ mpart) {
  if (blockIdx.x >= 140) {
    int p = blockIdx.x - 140;           // 0..255
    int b = p >> 4, part = p & 15;
    const float4* src = (const float4*)(sc + (size_t)b*160000) + part*2500;
    float s = 0.f;
    for (int i = threadIdx.x; i < 2500; i += 256) {
      float4 v = src[i];
      s += (v.x + v.y) + (v.z + v.w);
    }
    __shared__ float red[256];
    red[threadIdx.x] = s; __syncthreads();
    for (int off = 128; off > 0; off >>= 1) {
      if (threadIdx.x < off) red[threadIdx.x] += red[threadIdx.x + off];
      __syncthreads();
    }
    if (threadIdx.x == 0) mpart[p] = red[0];
    return;
  }
  int D = blockIdx.x*256 + threadIdx.x;     // 0..35839
  float v0, v1;
  if (D < 9216) {               // W_d1 B-frags (288 x 64), d = 32q+c
    int frag = D >> 8;  int t = frag >> 1, q = frag & 1;
    int rem = D & 255;  int lane = rem >> 2, dj = rem & 3;
    int c = lane & 31, h2 = lane >> 5;
    int k = 16*t + 8*h2 + 2*dj;
    int d = 32*q + c;
    v0 = W1[k*64 + d]; v1 = W1[(k+1)*64 + d];
  } else if (D < 11264) {       // W_d2 B-frags, K permuted: pair sources (p, p+32)
    int Dl = D - 9216;
    int frag = Dl >> 8; int t2 = frag >> 1, q = frag & 1;
    int rem = Dl & 255; int lane = rem >> 2, dj = rem & 3;
    int c = lane & 31, h2 = lane >> 5;
    int p = 8*t2 + 4*h2 + dj;
    int d = 32*q + c;
    v0 = W2[p*64 + d]; v1 = W2[(p+32)*64 + d];
  } else if (D < 31232) {       // W_e1 frags (416 x 96), sc features first, static at 400
    int Dl = D - 11264;
    int frag = Dl >> 8; int t = frag/3, ct = frag - 3*t;
    int rem = Dl & 255; int lane = rem >> 2, dj = rem & 3;
    int c = lane & 31, h2 = lane >> 5;
    int k0 = 16*t + 8*h2 + 2*dj, k1 = k0 + 1;
    int d = 32*ct + c;
    v0 = (k0 < 400) ? We1[(8+k0)*96 + d] : (k0 < 408 ? We1[(k0-400)*96 + d] : 0.f);
    v1 = (k1 < 400) ? We1[(8+k1)*96 + d] : (k1 < 408 ? We1[(k1-400)*96 + d] : 0.f);
  } else {                      // W_e2 frags (96 x 96), plain K order
    int Dl = D - 31232;
    int frag = Dl >> 8; int t = frag/3, ct = frag - 3*t;
    int rem = Dl & 255; int lane = rem >> 2, dj = rem & 3;
    int c = lane & 31, h2 = lane >> 5;
    int k = 16*t + 8*h2 + 2*dj;
    int d = 32*ct + c;
    v0 = We2[k*96 + d]; v1 = We2[(k+1)*96 + d];
  }
  wq[D] = pkrtz_u(v0, v1);
}

// ---------------- fused encoder, K-split across 4 waves (unchanged, measured OK) ---------------
__global__ __launch_bounds__(256) void enc_kernel(
    const float* __restrict__ sc, const float* __restrict__ nf,
    const float* __restrict__ smean, const float* __restrict__ sstd,
    const float* __restrict__ be1, const float* __restrict__ ae1,
    const float* __restrict__ be2, const float* __restrict__ ae2,
    const float* __restrict__ mpart, const u32* __restrict__ wq,
    f16* __restrict__ hout) {
  __shared__ u32 lds[12288 + 1664];
  const int tid = threadIdx.x;
  const int wid = tid >> 6, lane = tid & 63;
  const int c = lane & 31, h2 = lane >> 5;
  const int r0 = blockIdx.x * 32;
  {
    int row = tid >> 3, seg = tid & 7;
    int r = r0 + row;
    int b = r / 400;
    float ms = 0.f;
    const float4* mp4 = (const float4*)(mpart + 16*b);
#pragma unroll
    for (int k = 0; k < 4; ++k) { float4 v = mp4[k]; ms += (v.x+v.y)+(v.z+v.w); }
    float rm = 1.f / fmaxf(ms*(1.f/160000.f), 1e-8f);
    const float4* src = (const float4*)(sc + (size_t)r*400);
#pragma unroll
    for (int i = 0; i < 13; ++i) {
      int col4 = seg + 8*i;
      if (col4 < 100) {
        float4 v = src[col4];
        u32 lo = pkrtz_u(v.x*rm, v.y*rm);
        u32 hi = pkrtz_u(v.z*rm, v.w*rm);
        *(u64*)(lds + row*210 + col4*2) = (u64)lo | ((u64)hi << 32);
      }
    }
  }
  __syncthreads();
  int tb = (wid==0) ? 0 : (wid==1) ? 7 : (wid==2) ? 14 : 20;
  int te = (wid==0) ? 7 : (wid==1) ? 14 : (wid==2) ? 20 : 26;
  f32x16 acc[3] = {};
  const u32* wb1 = wq + 11264;
  for (int t = tb; t < te; ++t) {
    f16x8 af;
    if (t < 25) {
      H8 av;
      const u32* ap = lds + c*210 + 8*t + 4*h2;
      av.d[0] = *(const u64*)ap;
      av.d[1] = *(const u64*)(ap + 2);
      af = av.h;
    } else {
      af = (f16x8){};
      if (h2 == 0) {
        int r = r0 + c;
        float q0[8];
#pragma unroll
        for (int j = 0; j < 8; ++j)
          q0[j] = (nf[r*8 + j] - smean[j]) / (sstd[j] + 1e-8f);
        af = pack8(q0[0],q0[1],q0[2],q0[3],q0[4],q0[5],q0[6],q0[7]);
      }
    }
#pragma unroll
    for (int ct = 0; ct < 3; ++ct) {
      f16x8 bf = *(const f16x8*)(wb1 + ((t*3+ct)*64 + lane)*4);
      acc[ct] = __builtin_amdgcn_mfma_f32_32x32x16_f16(af, bf, acc[ct], 0,0,0);
    }
  }
  __syncthreads();
#pragma unroll
  for (int ct = 0; ct < 3; ++ct) {
    union { f32x16 v; float4 f[4]; } u; u.v = acc[ct];
#pragma unroll
    for (int i4 = 0; i4 < 4; ++i4)
      *(float4*)(lds + (((wid*3+ct)*4 + i4)*64 + lane)*4) = u.f[i4];
  }
  __syncthreads();
  f16* zb16 = (f16*)(lds + 12288);
  const float a1 = *ae1;
  if (wid < 3) {
    float bv = be1[32*wid + c];
    f32x16 s;
#pragma unroll
    for (int i = 0; i < 16; ++i) s[i] = bv;
#pragma unroll
    for (int w2 = 0; w2 < 4; ++w2) {
#pragma unroll
      for (int i4 = 0; i4 < 4; ++i4) {
        float4 f = *(const float4*)(lds + (((w2*3+wid)*4 + i4)*64 + lane)*4);
        s[4*i4+0] += f.x; s[4*i4+1] += f.y; s[4*i4+2] += f.z; s[4*i4+3] += f.w;
      }
    }
#pragma unroll
    for (int r = 0; r < 16; ++r) {
      float v = s[r]; v = fmaxf(v, a1*v);
      int row = (r & 3) + 8*(r >> 2) + 4*h2;
      zb16[row*104 + 32*wid + c] = (f16)v;
    }
  }
  __syncthreads();
  if (wid < 3) {
    const float a2 = *ae2;
    float bv = be2[32*wid + c];
    f32x16 acc2;
#pragma unroll
    for (int i = 0; i < 16; ++i) acc2[i] = bv;
    const u32* wb2 = wq + 31232;
#pragma unroll
    for (int t = 0; t < 6; ++t) {
      f16x8 af = *(const f16x8*)(zb16 + c*104 + 16*t + 8*h2);
      f16x8 bf = *(const f16x8*)(wb2 + ((t*3+wid)*64 + lane)*4);
      acc2 = __builtin_amdgcn_mfma_f32_32x32x16_f16(af, bf, acc2, 0,0,0);
    }
#pragma unroll
    for (int rr = 0; rr < 16; ++rr) {
      int row = (rr & 3) + 8*(rr >> 2) + 4*h2;
      float v = acc2[rr]; v = fmaxf(v, a2*v);
      hout[(r0 + row)*96 + 32*wid + c] = (f16)v;
    }
  }
}

// ---------------- decoder v5: hj in registers, hI LDS broadcast, full Wd1 in LDS --------------
// LDS (dwords): hI row-major [0,1536)  Wd1 ksteps 0..17 [1536,10752)  zbuf [10752,15360)
//             = 61,440 B (<= 64 KB/WG), 2 blocks/CU. launch_bounds(256,2) — NEVER 3 (R3/R9).
// hj: 6 f16x8 register frags per wave, loaded once per block from global (lane-16B, L2).
// hI reads are wave-broadcast (same address all lanes) -> conflict-free by definition.
__global__ __launch_bounds__(256, 2) void decoder_kernel(
    const f16* __restrict__ hbuf, const u32* __restrict__ wq,
    const float* __restrict__ b1, const float* __restrict__ b2,
    const float* __restrict__ ad1, const float* __restrict__ ad2,
    const float* __restrict__ W3, const float* __restrict__ b3p,
    float* __restrict__ out) {
  __shared__ alignas(16) u32 smem[15360];
  const int tid = threadIdx.x;
  // task decode
  int p = blockIdx.x;
  int b = p / NPAIRS, pr = p - b*NPAIRS;
  int I = 0;
  while (pr >= NT - I) { pr -= NT - I; ++I; }
  const int J = I + pr;
  // stage hI tile row-major (32 rows x 96 f16, row stride 48 dwords)
  {
    for (int idx = tid; idx < 384; idx += 256) {
      int rr = idx / 12, ch = idx - rr*12;
      int nb = I*32 + rr;
      nb = nb < NN ? nb : NN-1;
      *(float4*)(smem + rr*48 + ch*4) =
          *(const float4*)(hbuf + (size_t)(b*NN + nb)*HID + ch*8);
    }
  }
  // stage full Wd1 (2304 float4)
  {
    float4* dst = (float4*)(smem + 1536);
    const float4* srcw = (const float4*)wq;
#pragma unroll
    for (int k = 0; k < 9; ++k) dst[tid + 256*k] = srcw[tid + 256*k];
  }

  const int lane = tid & 63;
  const int wid  = tid >> 6;
  const int c = lane & 31, h2 = lane >> 5;
  // hj register frags (global, once per block; no sync needed)
  f16x8 hjr[6];
  {
    int nbJ = J*32 + c; nbJ = nbJ < NN ? nbJ : NN-1;
    const f16* hjrow = hbuf + (size_t)(b*NN + nbJ)*HID + 8*h2;
#pragma unroll
    for (int t = 0; t < 6; ++t) hjr[t] = *(const f16x8*)(hjrow + 16*t);
  }
  __syncthreads();

  const f16* hIlds = (const f16*)smem;
  const f16* wfr = (const f16*)(smem + 1536);
  u32* zb = smem + 10752 + wid*1152;
  f16x8 w2f[4][2];
#pragma unroll
  for (int t2 = 0; t2 < 4; ++t2) {
    w2f[t2][0] = *(const f16x8*)(wq + 9216 + ((t2*2+0)*64 + lane)*4);
    w2f[t2][1] = *(const f16x8*)(wq + 9216 + ((t2*2+1)*64 + lane)*4);
  }
  const float b1x = b1[c], b1y = b1[c+32];
  const float b2x = b2[c], b2y = b2[c+32];
  const float a1 = *ad1, a2 = *ad2, b3 = *b3p;
  const f16x2 a1v = pkrtz(a1, a1);
  const f16x2 a2v = pkrtz(a2, a2);
  const f16x2 w3p = pkrtz(W3[c], W3[c+32]);
  const f16x2 ones2 = pkrtz(1.f, 1.f);
  const int gj = J*32 + c;
  const int bofs = b*EDGES;

  for (int it = 0; it < 4; ++it) {
    const int i0 = it*8 + wid*2;                // i_loc for m=0 (m adds 1)
    const f16* hi0p = hIlds + (i0+0)*HID + 8*h2;
    const f16* hi1p = hIlds + (i0+1)*HID + 8*h2;
    f32x16 acc[2][2];
#pragma unroll
    for (int r = 0; r < 16; ++r) {
      acc[0][0][r] = b1x; acc[0][1][r] = b1y;
      acc[1][0][r] = b1x; acc[1][1][r] = b1y;
    }
    // layer 1: K=288 = 6 octet-steps x {sum, absdiff, prod}
#pragma unroll
    for (int t = 0; t < 6; ++t) {
      f16x8 bs0 = *(const f16x8*)(wfr + (((t   )*2+0)*64 + lane)*8);
      f16x8 bs1 = *(const f16x8*)(wfr + (((t   )*2+1)*64 + lane)*8);
      f16x8 bd0 = *(const f16x8*)(wfr + (((t+ 6)*2+0)*64 + lane)*8);
      f16x8 bd1 = *(const f16x8*)(wfr + (((t+ 6)*2+1)*64 + lane)*8);
      f16x8 bp0 = *(const f16x8*)(wfr + (((t+12)*2+0)*64 + lane)*8);
      f16x8 bp1 = *(const f16x8*)(wfr + (((t+12)*2+1)*64 + lane)*8);
      f16x8 hj = hjr[t];
#pragma unroll
      for (int m = 0; m < 2; ++m) {
        f16x8 hi = *(const f16x8*)((m ? hi1p : hi0p) + 16*t);
        f16x8 su = hi + hj;
        f16x8 di = habs8(hi - hj);
        f16x8 prd = hi * hj;
        acc[m][0] = __builtin_amdgcn_mfma_f32_32x32x16_f16(su, bs0, acc[m][0], 0,0,0);
        acc[m][1] = __builtin_amdgcn_mfma_f32_32x32x16_f16(su, bs1, acc[m][1], 0,0,0);
        acc[m][0] = __builtin_amdgcn_mfma_f32_32x32x16_f16(di, bd0, acc[m][0], 0,0,0);
        acc[m][1] = __builtin_amdgcn_mfma_f32_32x32x16_f16(di, bd1, acc[m][1], 0,0,0);
        acc[m][0] = __builtin_amdgcn_mfma_f32_32x32x16_f16(prd, bp0, acc[m][0], 0,0,0);
        acc[m][1] = __builtin_amdgcn_mfma_f32_32x32x16_f16(prd, bp1, acc[m][1], 0,0,0);
      }
    }
#pragma unroll
    for (int m = 0; m < 2; ++m) {
      // prelu(z1) packed-f16 -> LDS pairs (d, d+32) at dword [row][c], stride 36
#pragma unroll
      for (int r = 0; r < 16; ++r) {
        f16x2 pz = pkrtz(acc[m][0][r], acc[m][1][r]);
        pz = __builtin_elementwise_max(pz, pz * a1v);
        C2 cv; cv.h = pz;
        int row = (r & 3) + 8*(r >> 2) + 4*h2;
        zb[row*36 + c] = cv.u;
      }
      // read back as layer-2 A-frags (edge = c): permuted-K contiguous, aligned b128
      f16x8 za[4];
#pragma unroll
      for (int t2 = 0; t2 < 4; ++t2)
        za[t2] = *(const f16x8*)((const f16*)zb + (c*36 + 8*t2 + 4*h2)*2);
      f32x16 zacc[2];
#pragma unroll
      for (int r = 0; r < 16; ++r) { zacc[0][r] = b2x; zacc[1][r] = b2y; }
#pragma unroll
      for (int t2 = 0; t2 < 4; ++t2) {
        zacc[0] = __builtin_amdgcn_mfma_f32_32x32x16_f16(za[t2], w2f[t2][0], zacc[0], 0,0,0);
        zacc[1] = __builtin_amdgcn_mfma_f32_32x32x16_f16(za[t2], w2f[t2][1], zacc[1], 0,0,0);
      }
      // prelu(z2)*W3 packed -> LDS -> per-edge dot2 sum
#pragma unroll
      for (int r = 0; r < 16; ++r) {
        f16x2 pz = pkrtz(zacc[0][r], zacc[1][r]);
        pz = __builtin_elementwise_max(pz, pz * a2v);
        pz = pz * w3p;
        C2 cv; cv.h = pz;
        int row = (r & 3) + 8*(r >> 2) + 4*h2;
        zb[row*36 + c] = cv.u;
      }
      float ssum = 0.f;
#pragma unroll
      for (int g = 0; g < 4; ++g) {
        H8 v; v.h = *(const f16x8*)((const f16*)zb + (c*36 + 16*h2 + 4*g)*2);
#pragma unroll
        for (int dw = 0; dw < 4; ++dw)
          ssum = fdot2a(v.p[dw], ones2, ssum);
      }
      ssum += __shfl_xor(ssum, 32);
      // lane c holds edge (gi, gj=J*32+c); analytic triu index, coalesced in c
      int gi = I*32 + i0 + m;
      bool valid = (gi < gj) && (gj < NN);
      if (h2 == 0 && valid) {
        int eo = bofs + gi*(799 - gi)/2 + (gj - gi - 1);
        out[eo] = ssum + b3;
      }
    }
  }
}

extern "C" void kernel_launch(void* const* d_in, const int* in_sizes, int n_in,
                              void* d_out, int out_size, void* d_ws, size_t ws_size,
                              hipStream_t stream) {
  const float* nf  = (const float*)d_in[1];
  const float* sc  = (const float*)d_in[2];
  const float* sm  = (const float*)d_in[3];
  const float* ss  = (const float*)d_in[4];
  const float* We1 = (const float*)d_in[5];
  const float* be1 = (const float*)d_in[6];
  const float* ae1 = (const float*)d_in[7];
  const float* We2 = (const float*)d_in[8];
  const float* be2 = (const float*)d_in[9];
  const float* ae2 = (const float*)d_in[10];
  const float* W1  = (const float*)d_in[11];
  const float* b1  = (const float*)d_in[12];
  const float* a1  = (const float*)d_in[13];
  const float* W2  = (const float*)d_in[14];
  const float* b2  = (const float*)d_in[15];
  const float* a2  = (const float*)d_in[16];
  const float* W3  = (const float*)d_in[17];
  const float* b3  = (const float*)d_in[18];
  float* out = (float*)d_out;

  char* ws = (char*)d_ws;
  float* mpart = (float*)ws;                             // 256 f32 = 1,024 B
  f16*   hbuf = (f16*)(ws + 1024);                       // 1,228,800 B
  u32*   wq   = (u32*)(ws + 1024 + 1228800);             // 143,360 B

  prep_mean_kernel<<<396, 256, 0, stream>>>(We1, We2, W1, W2, sc, wq, mpart);
  enc_kernel<<<200, 256, 0, stream>>>(sc, nf, sm, ss, be1, ae1, be2, ae2,
                                      mpart, wq, hbuf);
  decoder_kernel<<<BATCH*NPAIRS, 256, 0, stream>>>(hbuf, wq, b1, b2, a1, a2,
                                                   W3, b3, out);
}